// Round 3
// baseline (452.601 us; speedup 1.0000x reference)
//
#include <hip/hip_runtime.h>

// Problem dims (fixed by setup_inputs)
#define D_  160
#define H_  192
#define W_  160
#define HW_ (H_*W_)          // 30720
#define N_  (D_*HW_)         // 4915200

#define SEGH 12              // H_/SEGH = 16 segments per column in pass AB
#define SEGD 10              // D_/SEGD = 16 segments per column in pass C

// ---------------------------------------------------------------- reductions
__device__ __forceinline__ float blockReduceSum(float v) {
    __shared__ float red_s[16];
    const int lane = threadIdx.x & 63;
    const int wid  = threadIdx.x >> 6;
    #pragma unroll
    for (int off = 32; off > 0; off >>= 1) v += __shfl_down(v, off, 64);
    __syncthreads();                  // protect red_s across repeated calls
    if (lane == 0) red_s[wid] = v;
    __syncthreads();
    const int nw = (blockDim.x + 63) >> 6;
    v = (threadIdx.x < nw) ? red_s[threadIdx.x] : 0.0f;
    if (wid == 0) {
        #pragma unroll
        for (int off = 8; off > 0; off >>= 1) v += __shfl_down(v, off, 64);
    }
    return v;  // valid on thread 0
}

// ------------------------------------------------- 9-tap W-sum of the 5 fields
__device__ __forceinline__ void wsum5(const float* __restrict__ I,
                                      const float* __restrict__ J,
                                      int rowbase, int w, float out[5]) {
    float sI = 0.f, sJ = 0.f, sII = 0.f, sJJ = 0.f, sIJ = 0.f;
    #pragma unroll
    for (int o = -4; o <= 4; ++o) {
        int x = w + o;
        if (x >= 0 && x < W_) {
            float a = I[rowbase + x];
            float b = J[rowbase + x];
            sI  += a;     sJ  += b;
            sII += a * a; sJJ += b * b; sIJ += a * b;
        }
    }
    out[0] = sI; out[1] = sJ; out[2] = sII; out[3] = sJJ; out[4] = sIJ;
}

// --------------------------------------------- pass AB: box-sum along W then H
// thread <-> (d, w, seg). Slides a 9-row register ring along H.
// out: 5 volumes (SoA) of W+H box sums.
__global__ void __launch_bounds__(256)
passAB(const float* __restrict__ I, const float* __restrict__ J,
       float* __restrict__ out) {
    int gtid = blockIdx.x * 256 + threadIdx.x;   // 409600 total, grid exact
    int w    = gtid % W_;
    int t    = gtid / W_;
    int d    = t % D_;
    int seg  = t / D_;
    int h0   = seg * SEGH;
    int dbase = d * HW_;

    float r[9][5];
    float s[5] = {0.f, 0.f, 0.f, 0.f, 0.f};
    #pragma unroll
    for (int k = 0; k < 9; ++k) {
        int y = h0 - 4 + k;
        if (y >= 0 && y < H_) {
            wsum5(I, J, dbase + y * W_, w, r[k]);
        } else {
            #pragma unroll
            for (int f = 0; f < 5; ++f) r[k][f] = 0.f;
        }
        #pragma unroll
        for (int f = 0; f < 5; ++f) s[f] += r[k][f];
    }

    for (int h = h0; h < h0 + SEGH; ++h) {
        int idx = dbase + h * W_ + w;
        #pragma unroll
        for (int f = 0; f < 5; ++f) out[f * N_ + idx] = s[f];

        float wnew[5];
        int y = h + 5;
        if (y < H_) {
            wsum5(I, J, dbase + y * W_, w, wnew);
        } else {
            #pragma unroll
            for (int f = 0; f < 5; ++f) wnew[f] = 0.f;
        }
        #pragma unroll
        for (int f = 0; f < 5; ++f) s[f] += wnew[f] - r[0][f];
        #pragma unroll
        for (int k = 0; k < 8; ++k) {
            #pragma unroll
            for (int f = 0; f < 5; ++f) r[k][f] = r[k + 1][f];
        }
        #pragma unroll
        for (int f = 0; f < 5; ++f) r[8][f] = wnew[f];
    }
}

// ------------------------------------- pass C: box-sum along D + cc + reduce
// thread <-> (h, w, seg). Sliding window along D (add leading, sub trailing).
__global__ void __launch_bounds__(256)
passC(const float* __restrict__ in, float* __restrict__ accum) {
    int gtid = blockIdx.x * 256 + threadIdx.x;   // 491520 total, grid exact
    int w    = gtid % W_;
    int t    = gtid / W_;
    int h    = t % H_;
    int seg  = t / H_;
    int d0   = seg * SEGD;
    int base = h * W_ + w;

    float s[5] = {0.f, 0.f, 0.f, 0.f, 0.f};
    #pragma unroll
    for (int f = 0; f < 5; ++f) {
        for (int z = d0 - 4; z <= d0 + 4; ++z) {
            if (z >= 0 && z < D_) s[f] += in[f * N_ + z * HW_ + base];
        }
    }

    const float inv = 1.0f / 729.0f;
    float acc = 0.0f;
    for (int d = d0; d < d0 + SEGD; ++d) {
        float sI = s[0], sJ = s[1], sII = s[2], sJJ = s[3], sIJ = s[4];
        float u_I = sI * inv, u_J = sJ * inv;
        float cross = sIJ - u_J * sI - u_I * sJ + u_I * u_J * 729.0f;
        float Ivar  = sII - 2.0f * u_I * sI + u_I * u_I * 729.0f;
        float Jvar  = sJJ - 2.0f * u_J * sJ + u_J * u_J * 729.0f;
        float cc = cross * cross / (Ivar * Jvar + 1e-5f);
        acc += cc;

        int za = d + 5, zb = d - 4;
        #pragma unroll
        for (int f = 0; f < 5; ++f) {
            float add = (za < D_)  ? in[f * N_ + za * HW_ + base] : 0.f;
            float sub = (zb >= 0)  ? in[f * N_ + zb * HW_ + base] : 0.f;
            s[f] += add - sub;
        }
    }

    float tot = blockReduceSum(acc);
    if (threadIdx.x == 0) atomicAdd(&accum[0], tot);
}

// ------------------------------------------------------ gradient (l2) penalty
__global__ void __launch_bounds__(256)
gradK(const float* __restrict__ s, float* __restrict__ accum) {
    float ax = 0.f, ay = 0.f, az = 0.f;   // H-diff, D-diff, W-diff
    const int total = 3 * N_;
    for (int idx = blockIdx.x * 256 + threadIdx.x; idx < total;
         idx += gridDim.x * 256) {
        int i2 = idx % N_;
        int d  = i2 / HW_;
        int r  = i2 % HW_;
        int h  = r / W_;
        int w  = r % W_;
        float c = s[idx];
        if (w < W_ - 1) { float t = s[idx + 1]   - c; az += t * t; }
        if (h < H_ - 1) { float t = s[idx + W_]  - c; ax += t * t; }
        if (d < D_ - 1) { float t = s[idx + HW_] - c; ay += t * t; }
    }
    ax = blockReduceSum(ax);
    ay = blockReduceSum(ay);
    az = blockReduceSum(az);
    if (threadIdx.x == 0) {
        atomicAdd(&accum[1], ax);
        atomicAdd(&accum[2], ay);
        atomicAdd(&accum[3], az);
    }
}

// ------------------------------------------------------------- final combine
__global__ void finalK(const float* __restrict__ accum, float* __restrict__ out) {
    const float Ncc = (float)N_;
    // 3 displacement channels: diff counts include the channel dimension!
    const float Nx  = (float)(3 * D_ * (H_ - 1) * W_);   // H-diff count
    const float Ny  = (float)(3 * (D_ - 1) * H_ * W_);   // D-diff count
    const float Nz  = (float)(3 * D_ * H_ * (W_ - 1));   // W-diff count
    float cc_mean = accum[0] / Ncc;
    float gd = accum[1] / Nx + accum[2] / Ny + accum[3] / Nz;
    out[0] = (1.0f - cc_mean) + 0.01f * gd / 3.0f;
}

// ---------------------------------------------------------------------- launch
extern "C" void kernel_launch(void* const* d_in, const int* in_sizes, int n_in,
                              void* d_out, int out_size, void* d_ws, size_t ws_size,
                              hipStream_t stream) {
    const float* I   = (const float*)d_in[0];   // y_fwd  (N_)
    const float* J   = (const float*)d_in[1];   // y_inv  (N_)
    const float* dsp = (const float*)d_in[2];   // dsp_fields (3*N_)
    float* out = (float*)d_out;

    float* bufB  = (float*)d_ws;                 // 5 * N_ floats (~98.3 MB)
    float* accum = bufB + (size_t)5 * N_;        // 4 floats

    hipMemsetAsync(accum, 0, 4 * sizeof(float), stream);

    // pass AB: 160*160*16 threads / 256 = 1600 blocks (exact)
    passAB<<<1600, 256, 0, stream>>>(I, J, bufB);
    // pass C: 192*160*16 threads / 256 = 1920 blocks (exact)
    passC<<<1920, 256, 0, stream>>>(bufB, accum);
    // gradient penalty
    gradK<<<4096, 256, 0, stream>>>(dsp, accum);
    // combine
    finalK<<<1, 1, 0, stream>>>(accum, out);
}

// Round 4
// 253.840 us; speedup vs baseline: 1.7830x; 1.7830x over previous
//
#include <hip/hip_runtime.h>

// Problem dims (fixed by setup_inputs)
#define D_   160
#define H_   192
#define W_   160
#define W4_  40              // W_/4
#define HW_  (H_*W_)         // 30720
#define HW4_ (HW_/4)         // 7680
#define N_   (D_*HW_)        // 4915200
#define NF4_ (N_/4)          // 1228800

#define SEGH   4
#define NSEGH  (H_/SEGH)     // 48
#define SEGD   5
#define NSEGD  (D_/SEGD)     // 32

#define ABBLOCKS 1200        // 40*160*48 / 256
#define CBLOCKS  960         // 40*192*32 / 256
#define GBLOCKS  2880
#define GITER    5           // 2880*256*5 = 3686400 = 3*N_/4

// ---------------------------------------------------------------- reductions
__device__ __forceinline__ float blockReduceSum(float v) {
    __shared__ float red_s[16];
    const int lane = threadIdx.x & 63;
    const int wid  = threadIdx.x >> 6;
    #pragma unroll
    for (int off = 32; off > 0; off >>= 1) v += __shfl_down(v, off, 64);
    __syncthreads();                  // protect red_s across repeated calls
    if (lane == 0) red_s[wid] = v;
    __syncthreads();
    const int nw = (blockDim.x + 63) >> 6;
    v = (threadIdx.x < nw) ? red_s[threadIdx.x] : 0.0f;
    if (wid == 0) {
        #pragma unroll
        for (int off = 8; off > 0; off >>= 1) v += __shfl_down(v, off, 64);
    }
    return v;  // valid on thread 0
}

// ----------------------------------------------------------- float4 helpers
__device__ __forceinline__ float4 f4add(float4 a, float4 b) {
    return make_float4(a.x+b.x, a.y+b.y, a.z+b.z, a.w+b.w);
}
__device__ __forceinline__ float4 f4sub(float4 a, float4 b) {
    return make_float4(a.x-b.x, a.y-b.y, a.z-b.z, a.w-b.w);
}

// 9-tap sums for 4 consecutive outputs from a 12-element window.
// lane o sums e[o..o+8]  (e[0] = w0-4 ... e[11] = w0+7)
__device__ __forceinline__ float4 win9(const float e[12]) {
    float a = ((e[0]+e[1])+(e[2]+e[3]))+((e[4]+e[5])+(e[6]+e[7]))+e[8];
    float b = a + e[9]  - e[0];
    float c = b + e[10] - e[1];
    float d = c + e[11] - e[2];
    return make_float4(a, b, c, d);
}

// W-window sums of the 5 fields for one input row (4 outputs per thread).
__device__ __forceinline__ void rowSums(const float4* __restrict__ I4,
                                        const float4* __restrict__ J4,
                                        int rb4, int w4,
                                        float4& rI, float4& rJ,
                                        float4& rII, float4& rJJ, float4& rIJ) {
    const float4 z = make_float4(0.f, 0.f, 0.f, 0.f);
    float4 iL = (w4 > 0)       ? I4[rb4 + w4 - 1] : z;
    float4 iC =                  I4[rb4 + w4];
    float4 iR = (w4 < W4_ - 1) ? I4[rb4 + w4 + 1] : z;
    float4 jL = (w4 > 0)       ? J4[rb4 + w4 - 1] : z;
    float4 jC =                  J4[rb4 + w4];
    float4 jR = (w4 < W4_ - 1) ? J4[rb4 + w4 + 1] : z;

    float eI[12] = {iL.x,iL.y,iL.z,iL.w, iC.x,iC.y,iC.z,iC.w, iR.x,iR.y,iR.z,iR.w};
    float eJ[12] = {jL.x,jL.y,jL.z,jL.w, jC.x,jC.y,jC.z,jC.w, jR.x,jR.y,jR.z,jR.w};
    float eII[12], eJJ[12], eIJ[12];
    #pragma unroll
    for (int k = 0; k < 12; ++k) {
        eII[k] = eI[k] * eI[k];
        eJJ[k] = eJ[k] * eJ[k];
        eIJ[k] = eI[k] * eJ[k];
    }
    rI  = win9(eI);
    rJ  = win9(eJ);
    rII = win9(eII);
    rJJ = win9(eJJ);
    rIJ = win9(eIJ);
}

// --------------------------------------------- pass AB: box-sum along W then H
// thread <-> (d, w4, hseg); 4 consecutive w outputs; slides along H with
// add(h+5)/sub(h-4), both rows RECOMPUTED from cache (no register ring).
__global__ void __launch_bounds__(256)
passAB(const float* __restrict__ I, const float* __restrict__ J,
       float* __restrict__ out) {
    const float4* I4 = (const float4*)I;
    const float4* J4 = (const float4*)J;
    float4* out4 = (float4*)out;

    int gtid = blockIdx.x * 256 + threadIdx.x;   // 307200 total, grid exact
    int w4   = gtid % W4_;
    int t    = gtid / W4_;
    int d    = t % D_;
    int hseg = t / D_;                            // 0..47
    int h0   = hseg * SEGH;
    int dbase4 = d * HW4_;

    float4 sI  = make_float4(0,0,0,0), sJ  = sI, sII = sI, sJJ = sI, sIJ = sI;

    // prime window rows h0-4 .. h0+4
    #pragma unroll 1
    for (int k = 0; k < 9; ++k) {
        int y = h0 - 4 + k;
        if (y < 0 || y >= H_) continue;
        float4 rI, rJ, rII, rJJ, rIJ;
        rowSums(I4, J4, dbase4 + y * W4_, w4, rI, rJ, rII, rJJ, rIJ);
        sI = f4add(sI, rI);  sJ = f4add(sJ, rJ);
        sII = f4add(sII, rII); sJJ = f4add(sJJ, rJJ); sIJ = f4add(sIJ, rIJ);
    }

    #pragma unroll 1
    for (int r = 0; r < SEGH; ++r) {
        int h  = h0 + r;
        int o4 = dbase4 + h * W4_ + w4;
        out4[0*NF4_ + o4] = sI;
        out4[1*NF4_ + o4] = sJ;
        out4[2*NF4_ + o4] = sII;
        out4[3*NF4_ + o4] = sJJ;
        out4[4*NF4_ + o4] = sIJ;
        if (r == SEGH - 1) break;
        int ya = h + 5, yb = h - 4;
        if (ya < H_) {
            float4 rI, rJ, rII, rJJ, rIJ;
            rowSums(I4, J4, dbase4 + ya * W4_, w4, rI, rJ, rII, rJJ, rIJ);
            sI = f4add(sI, rI);  sJ = f4add(sJ, rJ);
            sII = f4add(sII, rII); sJJ = f4add(sJJ, rJJ); sIJ = f4add(sIJ, rIJ);
        }
        if (yb >= 0) {
            float4 rI, rJ, rII, rJJ, rIJ;
            rowSums(I4, J4, dbase4 + yb * W4_, w4, rI, rJ, rII, rJJ, rIJ);
            sI = f4sub(sI, rI);  sJ = f4sub(sJ, rJ);
            sII = f4sub(sII, rII); sJJ = f4sub(sJJ, rJJ); sIJ = f4sub(sIJ, rIJ);
        }
    }
}

// --------------------------------------------------------- per-voxel cc value
__device__ __forceinline__ float ccf(float sI, float sJ, float sII,
                                     float sJJ, float sIJ) {
    const float inv = 1.0f / 729.0f;
    float cross = sIJ - sI * sJ * inv;
    float Iv    = sII - sI * sI * inv;
    float Jv    = sJJ - sJ * sJ * inv;
    return cross * cross / (Iv * Jv + 1e-5f);
}

// ------------------------------------- pass C: box-sum along D + cc + reduce
// thread <-> (w4, h, dseg); float4 over w; slides along D. NO atomics:
// per-block partial sums written to cPart[].
__global__ void __launch_bounds__(256)
passC(const float* __restrict__ in, float* __restrict__ cPart) {
    const float4* in4 = (const float4*)in;
    int gtid = blockIdx.x * 256 + threadIdx.x;   // 245760 total, grid exact
    int w4   = gtid % W4_;
    int t    = gtid / W4_;
    int h    = t % H_;
    int dseg = t / H_;                            // 0..31
    int d0   = dseg * SEGD;
    int base4 = h * W4_ + w4;

    float4 s0 = make_float4(0,0,0,0), s1 = s0, s2 = s0, s3 = s0, s4v = s0;

    #pragma unroll 1
    for (int z = d0 - 4; z <= d0 + 4; ++z) {
        if (z < 0 || z >= D_) continue;
        int a4 = z * HW4_ + base4;
        s0  = f4add(s0,  in4[0*NF4_ + a4]);
        s1  = f4add(s1,  in4[1*NF4_ + a4]);
        s2  = f4add(s2,  in4[2*NF4_ + a4]);
        s3  = f4add(s3,  in4[3*NF4_ + a4]);
        s4v = f4add(s4v, in4[4*NF4_ + a4]);
    }

    float acc = 0.0f;
    #pragma unroll 1
    for (int dd = 0; dd < SEGD; ++dd) {
        int d = d0 + dd;
        acc += ccf(s0.x, s1.x, s2.x, s3.x, s4v.x);
        acc += ccf(s0.y, s1.y, s2.y, s3.y, s4v.y);
        acc += ccf(s0.z, s1.z, s2.z, s3.z, s4v.z);
        acc += ccf(s0.w, s1.w, s2.w, s3.w, s4v.w);
        if (dd == SEGD - 1) break;
        int za = d + 5, zb = d - 4;
        if (za < D_) {
            int a4 = za * HW4_ + base4;
            s0  = f4add(s0,  in4[0*NF4_ + a4]);
            s1  = f4add(s1,  in4[1*NF4_ + a4]);
            s2  = f4add(s2,  in4[2*NF4_ + a4]);
            s3  = f4add(s3,  in4[3*NF4_ + a4]);
            s4v = f4add(s4v, in4[4*NF4_ + a4]);
        }
        if (zb >= 0) {
            int a4 = zb * HW4_ + base4;
            s0  = f4sub(s0,  in4[0*NF4_ + a4]);
            s1  = f4sub(s1,  in4[1*NF4_ + a4]);
            s2  = f4sub(s2,  in4[2*NF4_ + a4]);
            s3  = f4sub(s3,  in4[3*NF4_ + a4]);
            s4v = f4sub(s4v, in4[4*NF4_ + a4]);
        }
    }

    float tot = blockReduceSum(acc);
    if (threadIdx.x == 0) cPart[blockIdx.x] = tot;
}

// ------------------------------------------------------ gradient (l2) penalty
// float4 over w; per-block partials (pre-normalized per axis), NO atomics.
__global__ void __launch_bounds__(256)
gradK(const float* __restrict__ s, float* __restrict__ gPart) {
    const float4* s4 = (const float4*)s;
    const float invNx = 1.0f / (3.0f * D_ * (H_ - 1) * W_);   // h-diffs
    const float invNy = 1.0f / (3.0f * (D_ - 1) * H_ * W_);   // d-diffs
    const float invNz = 1.0f / (3.0f * D_ * H_ * (W_ - 1));   // w-diffs

    float acc = 0.0f;
    int tid0 = blockIdx.x * 256 + threadIdx.x;
    #pragma unroll 1
    for (int it = 0; it < GITER; ++it) {
        int f  = tid0 + it * (GBLOCKS * 256);
        int w4 = f % W4_;
        int t  = f / W4_;
        int h  = t % H_;
        int t2 = t / H_;
        int d  = t2 % D_;

        float4 A = s4[f];
        float wss = 0.f, hss = 0.f, dss = 0.f;
        { float a = A.y - A.x, b = A.z - A.y, c = A.w - A.z;
          wss = a*a + b*b + c*c; }
        if (w4 < W4_ - 1) { float b = s[f*4 + 4]; float u = b - A.w; wss += u*u; }
        if (h < H_ - 1) {
            float4 C = s4[f + W4_];
            float a = C.x-A.x, b = C.y-A.y, c = C.z-A.z, e = C.w-A.w;
            hss = a*a + b*b + c*c + e*e;
        }
        if (d < D_ - 1) {
            float4 Dv = s4[f + HW4_];
            float a = Dv.x-A.x, b = Dv.y-A.y, c = Dv.z-A.z, e = Dv.w-A.w;
            dss = a*a + b*b + c*c + e*e;
        }
        acc += wss * invNz + hss * invNx + dss * invNy;
    }

    float tot = blockReduceSum(acc);
    if (threadIdx.x == 0) gPart[blockIdx.x] = tot;
}

// ------------------------------------------------------------- final combine
__global__ void __launch_bounds__(256)
finalK(const float* __restrict__ cPart, const float* __restrict__ gPart,
       float* __restrict__ out) {
    float a = 0.f;
    for (int i = threadIdx.x; i < CBLOCKS; i += 256) a += cPart[i];
    float b = 0.f;
    for (int i = threadIdx.x; i < GBLOCKS; i += 256) b += gPart[i];
    float ccs = blockReduceSum(a);
    float gds = blockReduceSum(b);
    if (threadIdx.x == 0) {
        out[0] = (1.0f - ccs / (float)N_) + 0.01f * gds / 3.0f;
    }
}

// ---------------------------------------------------------------------- launch
extern "C" void kernel_launch(void* const* d_in, const int* in_sizes, int n_in,
                              void* d_out, int out_size, void* d_ws, size_t ws_size,
                              hipStream_t stream) {
    const float* I   = (const float*)d_in[0];   // y_fwd  (N_)
    const float* J   = (const float*)d_in[1];   // y_inv  (N_)
    const float* dsp = (const float*)d_in[2];   // dsp_fields (3*N_)
    float* out = (float*)d_out;

    float* buf   = (float*)d_ws;                 // 5 * N_ floats (~98.3 MB)
    float* cPart = buf + (size_t)5 * N_;         // CBLOCKS floats
    float* gPart = cPart + CBLOCKS;              // GBLOCKS floats

    passAB<<<ABBLOCKS, 256, 0, stream>>>(I, J, buf);
    passC <<<CBLOCKS,  256, 0, stream>>>(buf, cPart);
    gradK <<<GBLOCKS,  256, 0, stream>>>(dsp, gPart);
    finalK<<<1, 256, 0, stream>>>(cPart, gPart, out);
}